// Round 18
// baseline (159.452 us; speedup 1.0000x reference)
//
#include <hip/hip_runtime.h>

// Problem constants (fixed by setup_inputs):
//   a_arc, s_arc : [64, 1024, 1024] f32
//   adds, pos    : [64, 1024] int32 in [0, 50)
constexpr int NPOS  = 50;
constexpr int NBINS = NPOS * NPOS;   // 2500
constexpr int SL    = 1024;
constexpr int BZ    = 64;
constexpr float ALPHA = 0.3f;

using nat_f4 = __attribute__((ext_vector_type(4))) float;   // NT-loadable

// ---------------- hist (row-gather) config ----------------
constexpr int NRNG      = 8;                   // p-ranges {7,7,6,6,6,6,6,6}
constexpr int NHALF     = 2;                   // row halves (NEW vs R16)
constexpr int PSLICE    = 352;                 // per-block output slice (floats)
constexpr int H_THREADS = 256;                 // thread t owns cols 4t..4t+3
constexpr int H_BLOCKS  = BZ * NRNG * NHALF;   // 1024 -> 3 resident/CU + backfill

__device__ __forceinline__ int rng_lo(int r) { return r < 2 ? 7 * r : 14 + 6 * (r - 2); }
__device__ __forceinline__ int rng_sz(int r) { return r < 2 ? 7 : 6; }

// ---------------- reduce2 / apply config ----------------
constexpr int R2_THREADS = 256;
constexpr int R2_BLOCKS  = (NBINS + R2_THREADS - 1) / R2_THREADS;  // 10
constexpr int A_THREADS      = 256;
constexpr int ROWS_PER_BLOCK = 32;
constexpr int BLOCKS_PER_B   = SL / ROWS_PER_BLOCK;   // 32
constexpr int A_BLOCKS       = BZ * BLOCKS_PER_B;     // 2048

// ---------------------------------------------------------------------------
// Kernel 1: R16's verified NT gather hist, rows split 2x: 1024 blocks so a
// CU holds 3 resident blocks with a 4th queued — straggler blocks (binomial
// row counts) get backfilled instead of directly extending the kernel, and
// the serial sort prologue overlaps with another block's main loop.
// ---------------------------------------------------------------------------
__global__ __launch_bounds__(H_THREADS) void hist_gather(
    const float* __restrict__ a, const int* __restrict__ adds,
    float* __restrict__ g_part) {
  __shared__ int   adds_s[SL];          // 4 KB
  __shared__ float accL[8][SL];         // 32 KB: [p_loc][col]; slot 7 = dummy
  __shared__ int   list[512 + 8];       // 2 KB: (p_loc<<12)|row, sorted by p
  __shared__ int   order2[SL];          // 4 KB: cols sorted by q
  __shared__ int   cnt8[8], off8[8];
  __shared__ int   cntQ[NPOS], offQs[NPOS], offQm[NPOS];
  __shared__ int   nrows_s;

  const int tid  = threadIdx.x;
  const int b    = blockIdx.x / (NRNG * NHALF);
  const int rem  = blockIdx.x % (NRNG * NHALF);
  const int rg   = rem >> 1;
  const int half = rem & 1;
  const int lo   = rng_lo(rg), sz = rng_sz(rg);
  const int rlo  = half * (SL / NHALF), rhi = rlo + SL / NHALF;

  ((int4*)adds_s)[tid] = ((const int4*)(adds + (size_t)b * SL))[tid];
  #pragma unroll
  for (int p = 0; p < 8; ++p) ((float4*)&accL[p][0])[tid] = float4{0, 0, 0, 0};
  if (tid < 8) cnt8[tid] = 0;
  if (tid < NPOS) cntQ[tid] = 0;
  __syncthreads();

  // --- counting sorts: this half's range-rows by p_loc; ALL cols by q ---
  for (int i = tid; i < SL; i += H_THREADS) atomicAdd(&cntQ[adds_s[i]], 1);
  for (int i = rlo + tid; i < rhi; i += H_THREADS) {
    const int pl = adds_s[i] - lo;
    if ((unsigned)pl < (unsigned)sz) atomicAdd(&cnt8[pl], 1);
  }
  __syncthreads();
  if (tid == 0) {                       // wave 0: row prefix (8 entries)
    int run = 0;
    #pragma unroll
    for (int c = 0; c < 8; ++c) { off8[c] = run; run += cnt8[c]; }
    nrows_s = run;
  } else if (tid == 64) {               // wave 1: col prefix, concurrent
    int run = 0;
    for (int c = 0; c < NPOS; ++c) { offQs[c] = run; offQm[c] = run; run += cntQ[c]; }
  }
  __syncthreads();
  for (int i = rlo + tid; i < rhi; i += H_THREADS) {
    const int pl = adds_s[i] - lo;
    if ((unsigned)pl < (unsigned)sz)
      list[atomicAdd(&off8[pl], 1)] = (pl << 12) | i;
  }
  for (int i = tid; i < SL; i += H_THREADS)
    order2[atomicAdd(&offQm[adds_s[i]], 1)] = i;
  __syncthreads();
  const int N    = nrows_s;
  const int Npad = (N + 7) & ~7;
  if (tid < 8 && N + tid < Npad)        // pad: sentinel p_loc=7, valid row
    list[N + tid] = (7 << 12) | (N > 0 ? (list[N - 1] & 0xFFF) : 0);
  __syncthreads();

  // --- main loop: stream sorted rows, 8-deep ping-pong, NT 4-KB rows ---
  const nat_f4* __restrict__ Ab = (const nat_f4*)(a + (size_t)b * SL * SL);
  float4 creg = {0, 0, 0, 0};
  int pcur = 7;

  int    eA[8], eB[8];
  nat_f4 vA[8], vB[8];
  auto loadbank = [&](int (&e)[8], nat_f4 (&v)[8], int k) {
    #pragma unroll
    for (int u = 0; u < 8; ++u) {
      e[u] = __builtin_amdgcn_readfirstlane(list[k + u]);  // uniform -> SGPR
      v[u] = __builtin_nontemporal_load(
          Ab + (size_t)(e[u] & 0xFFF) * (SL / 4) + tid);   // NT 1 KB/wave-instr
    }
  };
  auto procbank = [&](int (&e)[8], nat_f4 (&v)[8]) {
    #pragma unroll
    for (int u = 0; u < 8; ++u) {
      const int pl = e[u] >> 12;
      if (pl != pcur) {                 // block-uniform scalar branch
        ((float4*)&accL[pcur][0])[tid] = creg;   // one store per p-run
        creg = float4{0, 0, 0, 0};
        pcur = pl;
      }
      creg.x += v[u][0]; creg.y += v[u][1]; creg.z += v[u][2]; creg.w += v[u][3];
    }
  };

  if (Npad > 0) {
    pcur = list[0] >> 12;
    loadbank(eA, vA, 0);
    for (int k = 0; k < Npad; k += 16) {
      if (k + 8 < Npad) loadbank(eB, vB, k + 8);
      procbank(eA, vA);
      if (k + 16 < Npad) loadbank(eA, vA, k + 16);
      if (k + 8 < Npad) procbank(eB, vB);
    }
    ((float4*)&accL[pcur][0])[tid] = creg;       // final flush (7 = dummy ok)
  }
  __syncthreads();

  // --- col reduce: slice[pl*50+q] = sum_{cols j: adds[j]==q} accL[pl][j] ---
  float* __restrict__ gp = g_part + (size_t)blockIdx.x * PSLICE;
  for (int bin = tid; bin < sz * NPOS; bin += H_THREADS) {
    const int pl = bin / NPOS, q = bin % NPOS;
    const int s0 = offQs[q], n = cntQ[q];
    float s = 0.0f;
    for (int k2 = 0; k2 < n; ++k2) s += accL[pl][order2[s0 + k2]];
    gp[bin] = s;                        // plain store, private slice
  }
}

// ---------------------------------------------------------------------------
// Kernel 1.5: g_hist[bin] = sum over 64 batches x 2 halves of that bin's
// range-slice. Plain stores; one thread per bin -> no atomics, no memset.
// ---------------------------------------------------------------------------
__global__ __launch_bounds__(R2_THREADS) void reduce2(
    const float* __restrict__ g_part, float* __restrict__ g_hist) {
  const int bin = blockIdx.x * R2_THREADS + threadIdx.x;
  if (bin >= NBINS) return;
  const int p = bin / NPOS, q = bin % NPOS;
  const int rg = (p < 14) ? p / 7 : 2 + (p - 14) / 6;
  const int pl = (p < 14) ? p % 7 : (p - 14) % 6;
  const float* __restrict__ base =
      g_part + (size_t)(rg * NHALF) * PSLICE + pl * NPOS + q;
  float s = 0.0f;
  #pragma unroll 8
  for (int bb = 0; bb < BZ; ++bb) {
    const size_t o = (size_t)bb * (NRNG * NHALF) * PSLICE;
    s += base[o] + base[o + PSLICE];
  }
  g_hist[bin] = s;
}

// ---------------------------------------------------------------------------
// Kernel 2: out = s_arc + ALPHA * sigmoid(g_hist)[pos-pair bin].
// R16-verified: NT load of s_arc + NT store of out; ~6.6 TB/s combined.
// ---------------------------------------------------------------------------
__global__ __launch_bounds__(A_THREADS) void apply_kernel(
    const float* __restrict__ s, const int* __restrict__ pos,
    const float* __restrict__ g_hist, float* __restrict__ out) {
  __shared__ float sig[NBINS];
  __shared__ int   pos_s[SL];

  const int tid = threadIdx.x;
  const int b   = blockIdx.x / BLOCKS_PER_B;
  const int i0  = (blockIdx.x % BLOCKS_PER_B) * ROWS_PER_BLOCK;

  ((int4*)pos_s)[tid] = ((const int4*)(pos + (size_t)b * SL))[tid];
  for (int k = tid; k < NBINS; k += A_THREADS) {
    const float h = g_hist[k];
    sig[k] = 1.0f / (1.0f + __expf(-h));
  }
  __syncthreads();

  const int4 pj = ((const int4*)pos_s)[tid];
  const size_t rowoff = ((size_t)b * SL + i0) * SL;
  const nat_f4* __restrict__ srow = (const nat_f4*)(s + rowoff);
  nat_f4* __restrict__ orow = (nat_f4*)(out + rowoff);

  for (int r = 0; r < ROWS_PER_BLOCK; ++r) {
    const int base = pos_s[i0 + r] * NPOS;    // wave-uniform broadcast
    const nat_f4 sv =
        __builtin_nontemporal_load(srow + (size_t)r * (SL / 4) + tid);
    nat_f4 ov;
    ov[0] = sv[0] + ALPHA * sig[base + pj.x];
    ov[1] = sv[1] + ALPHA * sig[base + pj.y];
    ov[2] = sv[2] + ALPHA * sig[base + pj.z];
    ov[3] = sv[3] + ALPHA * sig[base + pj.w];
    __builtin_nontemporal_store(ov, orow + (size_t)r * (SL / 4) + tid);
  }
}

extern "C" void kernel_launch(void* const* d_in, const int* in_sizes, int n_in,
                              void* d_out, int out_size, void* d_ws, size_t ws_size,
                              hipStream_t stream) {
  const float* a_arc = (const float*)d_in[0];
  const float* s_arc = (const float*)d_in[1];
  const int*   adds  = (const int*)d_in[2];
  const int*   pos   = (const int*)d_in[3];
  float* out    = (float*)d_out;
  float* g_hist = (float*)d_ws;                 // 2500 floats
  float* g_part = g_hist + 4096;                // 1024 x 352 floats = 1.4 MB

  // No memset needed: g_part slices and g_hist are fully overwritten with
  // plain stores every call (no atomic accumulation anywhere).
  hist_gather <<<H_BLOCKS, H_THREADS, 0, stream>>>(a_arc, adds, g_part);
  reduce2     <<<R2_BLOCKS, R2_THREADS, 0, stream>>>(g_part, g_hist);
  apply_kernel<<<A_BLOCKS, A_THREADS, 0, stream>>>(s_arc, pos, g_hist, out);
}